// Round 1
// baseline (255.451 us; speedup 1.0000x reference)
//
#include <hip/hip_runtime.h>

#define BATCH 2
#define SS    256   // 16x16 subdomain grid
#define CC    128
#define HWN   256   // 16x16 spatial
#define NHEAD 8
#define FDIM  4096  // 64 ch * 8 * 8 per head

typedef unsigned int uint;
typedef unsigned short ushort;
typedef short bf16x8 __attribute__((ext_vector_type(8)));
typedef float f32x4 __attribute__((ext_vector_type(4)));

__device__ __forceinline__ ushort f2b(float f) {
  uint u = __float_as_uint(f);
  return (ushort)((u + 0x7fffu + ((u >> 16) & 1u)) >> 16);  // RNE
}
__device__ __forceinline__ float b2f(ushort h) { return __uint_as_float((uint)h << 16); }

// ---------------- K0: convert weights to bf16 ----------------
__global__ void k_convert(const float* __restrict__ wqkv, const float* __restrict__ wout,
                          ushort* __restrict__ wqkv_b, ushort* __restrict__ wout_b) {
  int i = blockIdx.x * 256 + threadIdx.x;
  if (i < 384 * 128) wqkv_b[i] = f2b(wqkv[i]);
  if (i < 128 * 128) wout_b[i] = f2b(wout[i]);
}

// ---------------- K1: qkv projection + head scatter ----------------
// Per block: one (b,s). GEMM [384 x 128] @ [128 x 256] in 16x16x32 bf16 MFMA.
// qkvh layout: [(qkvi*16 + b*8 + n)][s][f], f = c*64+hwl for q,k ; hwl*64+c for v.
__global__ __launch_bounds__(256) void k_qkv(const float* __restrict__ seq,
                                             const ushort* __restrict__ wqkv_b,
                                             ushort* __restrict__ qkvh) {
  const int bs = blockIdx.x;
  const int b = bs >> 8, s = bs & 255;
  const int t = threadIdx.x;
  const int wave = t >> 6, lane = t & 63;
  const int qq = lane >> 4, m = lane & 15;

  const float* sp = seq + (size_t)bs * (CC * HWN);

  // B fragments: bfrag[ntp][ks] elem j = bf16(seq[k=ks*32+qq*8+j][hw=(wave*4+ntp)*16+m])
  bf16x8 bfrag[4][4];
  #pragma unroll
  for (int ntp = 0; ntp < 4; ++ntp) {
    const int hw = (wave * 4 + ntp) * 16 + m;
    #pragma unroll
    for (int ks = 0; ks < 4; ++ks) {
      const int k0 = ks * 32 + qq * 8;
      float tmp[8];
      #pragma unroll
      for (int j = 0; j < 8; ++j) tmp[j] = sp[(k0 + j) * HWN + hw];
      bf16x8 fr;
      #pragma unroll
      for (int j = 0; j < 8; ++j) fr[j] = (short)f2b(tmp[j]);
      bfrag[ntp][ks] = fr;
    }
  }

  for (int mt = 0; mt < 24; ++mt) {
    bf16x8 afrag[4];
    const ushort* ap = wqkv_b + (mt * 16 + m) * CC;
    #pragma unroll
    for (int ks = 0; ks < 4; ++ks) afrag[ks] = *(const bf16x8*)(ap + ks * 32 + qq * 8);
    const int qkvi = mt >> 3;          // 0=q 1=k 2=v (tile of 16 d stays within one)
    const int ch   = (mt >> 2) & 1;    // channel head
    #pragma unroll
    for (int ntp = 0; ntp < 4; ++ntp) {
      f32x4 acc = {0.f, 0.f, 0.f, 0.f};
      #pragma unroll
      for (int ks = 0; ks < 4; ++ks)
        acc = __builtin_amdgcn_mfma_f32_16x16x32_bf16(afrag[ks], bfrag[ntp][ks], acc, 0, 0, 0);
      const int ntg = wave * 4 + ntp;                       // == hy (hw row)
      const int n   = ((ntg >> 3) * 2 + (m >> 3)) * 2 + ch; // head
      const int hwl = (ntg & 7) * 8 + (m & 7);              // local spatial idx
      const size_t base = ((size_t)(qkvi * 16 + b * 8 + n) * SS + s) * FDIM;
      #pragma unroll
      for (int r = 0; r < 4; ++r) {
        const int c = (mt & 3) * 16 + qq * 4 + r;           // channel within head
        const int f = (qkvi == 2) ? (hwl * 64 + c) : (c * 64 + hwl);
        qkvh[base + f] = f2b(acc[r]);
      }
    }
  }
}

// ---------------- K2: masked scores + softmax -> 9 weights per (b,n,s) --------
__global__ __launch_bounds__(256) void k_scores(const ushort* __restrict__ qkvh,
                                                float* __restrict__ attn) {
  const int wid = blockIdx.x * 4 + (threadIdx.x >> 6);
  const int lane = threadIdx.x & 63;
  const int b = wid >> 11;
  const int n = (wid >> 8) & 7;
  const int s = wid & 255;
  const int sy = s >> 4, sx = s & 15;
  const size_t hs = (size_t)SS * FDIM;

  const ushort* qp = qkvh + (size_t)(b * 8 + n) * hs + (size_t)s * FDIM + lane * 8;
  bf16x8 qf[8];
  #pragma unroll
  for (int i = 0; i < 8; ++i) qf[i] = *(const bf16x8*)(qp + i * 512);

  float sc[9];
  #pragma unroll
  for (int j = 0; j < 9; ++j) {
    const int dy = j / 3 - 1, dx = j % 3 - 1;
    const int ny = sy + dy, nx = sx + dx;
    const bool valid = (ny >= 0 && ny < 16 && nx >= 0 && nx < 16);
    const int sj = valid ? (ny * 16 + nx) : s;
    const ushort* kp = qkvh + (size_t)(16 + b * 8 + n) * hs + (size_t)sj * FDIM + lane * 8;
    float acc = 0.f;
    #pragma unroll
    for (int i = 0; i < 8; ++i) {
      bf16x8 kf = *(const bf16x8*)(kp + i * 512);
      #pragma unroll
      for (int e = 0; e < 8; ++e) acc += b2f((ushort)qf[i][e]) * b2f((ushort)kf[e]);
    }
    #pragma unroll
    for (int off = 32; off > 0; off >>= 1) acc += __shfl_xor(acc, off);
    sc[j] = valid ? acc * (1.f / 64.f) : -1e30f;
  }
  float mx = sc[0];
  #pragma unroll
  for (int j = 1; j < 9; ++j) mx = fmaxf(mx, sc[j]);
  float sum = 0.f, p[9];
  #pragma unroll
  for (int j = 0; j < 9; ++j) { p[j] = __expf(sc[j] - mx); sum += p[j]; }
  const float inv = 1.f / sum;
  if (lane < 9) {
    float v = p[0];
    #pragma unroll
    for (int j = 1; j < 9; ++j) v = (lane == j) ? p[j] : v;
    attn[((size_t)(b * 8 + n) * SS + s) * 9 + lane] = v * inv;
  }
}

// ---------------- K3: PV (in B-fragment layout) + out projection --------------
__global__ __launch_bounds__(256) void k_out(const ushort* __restrict__ qkvh,
                                             const float* __restrict__ attn,
                                             const ushort* __restrict__ wout_b,
                                             const float* __restrict__ bout,
                                             float* __restrict__ out) {
  const int bs = blockIdx.x;
  const int b = bs >> 8, s = bs & 255;
  const int t = threadIdx.x;
  const int wave = t >> 6, lane = t & 63;
  const int qq = lane >> 4, m = lane & 15;
  const int sy = s >> 4, sx = s & 15;
  const size_t hs = (size_t)SS * FDIM;

  int sjc[9];
  #pragma unroll
  for (int j = 0; j < 9; ++j) {
    const int ny = min(max(sy + j / 3 - 1, 0), 15);
    const int nx = min(max(sx + j % 3 - 1, 0), 15);
    sjc[j] = ny * 16 + nx;
  }

  // yh is constant per wave (ntg = wave*4+ntp ; ntg>>3 == wave>>1)
  const int yh = wave >> 1;
  const int nbase = (yh * 2 + (m >> 3)) * 2;  // + ch
  float pch[2][9];
  #pragma unroll
  for (int ch = 0; ch < 2; ++ch) {
    #pragma unroll
    for (int j = 0; j < 9; ++j)
      pch[ch][j] = attn[((size_t)(b * 8 + nbase + ch) * SS + s) * 9 + j];
  }

  // sa in MFMA B-fragment layout: B[cc=ks*32+qq*8+j][hw=ntg*16+m]
  bf16x8 bfrag[4][4];
  #pragma unroll
  for (int ntp = 0; ntp < 4; ++ntp) {
    const int ntg = wave * 4 + ntp;
    const int hwl = (ntg & 7) * 8 + (m & 7);
    #pragma unroll
    for (int ks = 0; ks < 4; ++ks) {
      const int ch = ks >> 1;
      const int c0 = (ks * 32 + qq * 8) & 63;
      const ushort* vb = qkvh + (size_t)(32 + b * 8 + nbase + ch) * hs;
      float facc[8] = {0.f, 0.f, 0.f, 0.f, 0.f, 0.f, 0.f, 0.f};
      #pragma unroll
      for (int j = 0; j < 9; ++j) {
        bf16x8 vv = *(const bf16x8*)(vb + (size_t)sjc[j] * FDIM + hwl * 64 + c0);
        const float pj = pch[ch][j];
        #pragma unroll
        for (int e = 0; e < 8; ++e) facc[e] += pj * b2f((ushort)vv[e]);
      }
      bf16x8 fr;
      #pragma unroll
      for (int e = 0; e < 8; ++e) fr[e] = (short)f2b(facc[e]);
      bfrag[ntp][ks] = fr;
    }
  }

  // out[d][hw] = wout[d][cc] @ sa[cc][hw] + bout[d]
  #pragma unroll
  for (int mt = 0; mt < 8; ++mt) {
    bf16x8 afrag[4];
    const ushort* ap = wout_b + (mt * 16 + m) * CC;
    #pragma unroll
    for (int ks = 0; ks < 4; ++ks) afrag[ks] = *(const bf16x8*)(ap + ks * 32 + qq * 8);
    #pragma unroll
    for (int ntp = 0; ntp < 4; ++ntp) {
      f32x4 acc = {0.f, 0.f, 0.f, 0.f};
      #pragma unroll
      for (int ks = 0; ks < 4; ++ks)
        acc = __builtin_amdgcn_mfma_f32_16x16x32_bf16(afrag[ks], bfrag[ntp][ks], acc, 0, 0, 0);
      const int hw = (wave * 4 + ntp) * 16 + m;
      #pragma unroll
      for (int r = 0; r < 4; ++r) {
        const int d = mt * 16 + qq * 4 + r;
        out[((size_t)bs * CC + d) * HWN + hw] = acc[r] + bout[d];
      }
    }
  }
}

extern "C" void kernel_launch(void* const* d_in, const int* in_sizes, int n_in,
                              void* d_out, int out_size, void* d_ws, size_t ws_size,
                              hipStream_t stream) {
  const float* seq  = (const float*)d_in[0];
  const float* wqkv = (const float*)d_in[1];
  const float* wout = (const float*)d_in[2];
  const float* bout = (const float*)d_in[3];
  char* ws = (char*)d_ws;
  // ws layout (bytes): wqkv_b 98304 | wout_b 32768 | qkvh 100663296 | attn 147456
  ushort* wqkv_b = (ushort*)(ws);
  ushort* wout_b = (ushort*)(ws + 98304);
  ushort* qkvh   = (ushort*)(ws + 131072);
  float*  attn   = (float*)(ws + 131072 + 100663296ull);
  float*  outp   = (float*)d_out;

  hipLaunchKernelGGL(k_convert, dim3(192), dim3(256), 0, stream, wqkv, wout, wqkv_b, wout_b);
  hipLaunchKernelGGL(k_qkv,     dim3(512), dim3(256), 0, stream, seq, wqkv_b, qkvh);
  hipLaunchKernelGGL(k_scores,  dim3(1024), dim3(256), 0, stream, qkvh, attn);
  hipLaunchKernelGGL(k_out,     dim3(512), dim3(256), 0, stream, qkvh, attn, wout_b, bout, outp);
}